// Round 1
// 976.313 us; speedup vs baseline: 1.0862x; 1.0862x over previous
//
#include <hip/hip_runtime.h>
#include <hip/hip_bf16.h>

typedef __hip_bfloat16 bf16;
typedef short short8 __attribute__((ext_vector_type(8)));
typedef float f32x4 __attribute__((ext_vector_type(4)));

#define B_ 2
#define S_ 2048
#define HID_ 1024
#define H_ 16
#define D_ 64
#define M_ (B_*S_)   // 4096 token rows

__device__ __forceinline__ void gload16(const bf16* g, bf16* l) {
    __builtin_amdgcn_global_load_lds(
        (const __attribute__((address_space(1))) unsigned int*)g,
        (__attribute__((address_space(3))) unsigned int*)l, 16, 0, 0);
}

__device__ __forceinline__ f32x4 mfma16(short8 a, short8 b, f32x4 c) {
    return __builtin_amdgcn_mfma_f32_16x16x32_bf16(a, b, c, 0, 0, 0);
}

// ---------------- small prep kernels ----------------

__global__ void k_convert_x(const float* __restrict__ in, bf16* __restrict__ out, int n) {
    int i = blockIdx.x * blockDim.x + threadIdx.x;
    if (i * 4 < n) {
        float4 v = ((const float4*)in)[i];
        out[i*4+0] = __float2bfloat16(v.x);
        out[i*4+1] = __float2bfloat16(v.y);
        out[i*4+2] = __float2bfloat16(v.z);
        out[i*4+3] = __float2bfloat16(v.w);
    }
}

// W [K=in rows][N=out cols] fp32 -> Wt [N][K] bf16, z picks which weight
__global__ void k_trans_w(const float* W0, const float* W1, const float* W2, const float* W3,
                          bf16* T0, bf16* T1, bf16* T2, bf16* T3) {
    const float* W = blockIdx.z==0 ? W0 : blockIdx.z==1 ? W1 : blockIdx.z==2 ? W2 : W3;
    bf16*       T = blockIdx.z==0 ? T0 : blockIdx.z==1 ? T1 : blockIdx.z==2 ? T2 : T3;
    __shared__ float tile[32][33];
    int tx = threadIdx.x, ty = threadIdx.y;
    int k0 = blockIdx.x * 32, n0 = blockIdx.y * 32;
#pragma unroll
    for (int j = 0; j < 4; j++)
        tile[ty + j*8][tx] = W[(size_t)(k0 + ty + j*8) * HID_ + n0 + tx];
    __syncthreads();
#pragma unroll
    for (int j = 0; j < 4; j++)
        T[(size_t)(n0 + ty + j*8) * HID_ + k0 + tx] = __float2bfloat16(tile[tx][ty + j*8]);
}

// keyBias[b,h,k] = attn_mask[b,k] + hb[h]*hm[b,k] + mb[h]*mm[b,k] + eb[h]*em[b,k]
__global__ void k_keybias(const float* __restrict__ am, const float* __restrict__ hm,
                          const float* __restrict__ mm, const float* __restrict__ em,
                          const float* __restrict__ hb, const float* __restrict__ mb,
                          const float* __restrict__ eb, float* __restrict__ kb) {
    int i = blockIdx.x * blockDim.x + threadIdx.x;   // < B*H*S = 65536
    int kk = i & (S_ - 1);
    int bh = i >> 11;
    int h = bh & (H_ - 1);
    int b = bh >> 4;
    int bk = b * S_ + kk;
    kb[i] = am[bk] + hb[h]*hm[bk] + mb[h]*mm[bk] + eb[h]*em[bk];
}

// v [bh][s][d] -> vT [bh][d][s], bf16
__global__ void k_trans_v(const bf16* __restrict__ v, bf16* __restrict__ vT) {
    __shared__ bf16 tile[32][33];
    int bh = blockIdx.z;
    int s0 = blockIdx.x * 32, d0 = blockIdx.y * 32;
    int tx = threadIdx.x, ty = threadIdx.y;
    const bf16* vb = v + (size_t)bh * S_ * D_;
    bf16* vTb = vT + (size_t)bh * D_ * S_;
#pragma unroll
    for (int j = 0; j < 4; j++)
        tile[ty + j*8][tx] = vb[(size_t)(s0 + ty + j*8) * D_ + d0 + tx];
    __syncthreads();
#pragma unroll
    for (int j = 0; j < 4; j++)
        vTb[(size_t)(d0 + ty + j*8) * S_ + s0 + tx] = tile[tx][ty + j*8];
}

// ---------------- 128x128 MFMA GEMM: C = A[M,K] @ Bt[N,K]^T + bias ----------------
// SPLIT=true : out bf16 to [bh][s][d] layout (z=0:q scaled 1/8, 1:k, 2:v)
// SPLIT=false: out fp32 row-major [M, HID]
template<bool SPLIT>
__global__ __launch_bounds__(256) void k_gemm(
    const bf16* __restrict__ A,
    const bf16* __restrict__ Bt0, const bf16* __restrict__ Bt1, const bf16* __restrict__ Bt2,
    const float* __restrict__ bi0, const float* __restrict__ bi1, const float* __restrict__ bi2,
    bf16* d0, bf16* d1, bf16* d2, float* dF)
{
    const int K = HID_;
    int z = blockIdx.z;
    const bf16* Bt = (z==0) ? Bt0 : (z==1 ? Bt1 : Bt2);
    const float* bias = (z==0) ? bi0 : (z==1 ? bi1 : bi2);
    bf16* dst = (z==0) ? d0 : (z==1 ? d1 : d2);
    float scale = (SPLIT && z==0) ? 0.125f : 1.0f;

    __shared__ bf16 As[128*32];
    __shared__ bf16 Bs[128*32];
    int t = threadIdx.x;
    int lane = t & 63, wave = t >> 6;
    int wm = wave >> 1, wn = wave & 1;
    int bm = blockIdx.y * 128, bn = blockIdx.x * 128;

    f32x4 acc[4][4];
#pragma unroll
    for (int i = 0; i < 4; i++)
#pragma unroll
        for (int j = 0; j < 4; j++) acc[i][j] = f32x4{0.f, 0.f, 0.f, 0.f};

    const bf16* aG = A  + (size_t)(bm + (t >> 2)) * K + (t & 3) * 8;
    const bf16* bG = Bt + (size_t)(bn + (t >> 2)) * K + (t & 3) * 8;
    bf16* asD = As + t * 8;
    bf16* bsD = Bs + t * 8;
    int r16 = lane & 15, kq = (lane >> 4) * 8;

    for (int k0 = 0; k0 < K; k0 += 32) {
        __syncthreads();
        gload16(aG + k0,          asD);
        gload16(aG + 64*K + k0,   asD + 2048);
        gload16(bG + k0,          bsD);
        gload16(bG + 64*K + k0,   bsD + 2048);
        __syncthreads();
        short8 af[4], bfv[4];
#pragma unroll
        for (int mt = 0; mt < 4; mt++)
            af[mt] = *(const short8*)(As + (wm*64 + mt*16 + r16) * 32 + kq);
#pragma unroll
        for (int nt = 0; nt < 4; nt++)
            bfv[nt] = *(const short8*)(Bs + (wn*64 + nt*16 + r16) * 32 + kq);
#pragma unroll
        for (int mt = 0; mt < 4; mt++)
#pragma unroll
            for (int nt = 0; nt < 4; nt++)
                acc[mt][nt] = mfma16(af[mt], bfv[nt], acc[mt][nt]);
    }

    int quad = lane >> 4;
#pragma unroll
    for (int mt = 0; mt < 4; mt++) {
#pragma unroll
        for (int nt = 0; nt < 4; nt++) {
            int c = bn + wn*64 + nt*16 + r16;
            int rbase = bm + wm*64 + mt*16 + quad*4;
            float bv = bias[c];
#pragma unroll
            for (int r = 0; r < 4; r++) {
                int m = rbase + r;
                float v = acc[mt][nt][r] + bv;
                if constexpr (SPLIT) {
                    v *= scale;
                    int bb = m >> 11, ss = m & 2047, hh = c >> 6, dd = c & 63;
                    dst[(((size_t)bb * H_ + hh) * S_ + ss) * D_ + dd] = __float2bfloat16(v);
                } else {
                    dF[(size_t)m * HID_ + c] = v;
                }
            }
        }
    }
}

// ---------------- fused attention: single-pass, scores resident in registers ----------------
// grid: (qt=128, bh=32), block 256 (4 waves). Each block: 16 q-rows; wave w owns keys
// [w*512, (w+1)*512). Scores (32 x f32x4 = 128 VGPR) stay in registers: QK^T computed ONCE,
// exact fp32 probs written from registers, bf16 P round-trips wave-private LDS for PV.
// O-partials combined across the 4 key-split waves via LDS (overlaid on dead P tile).
__global__ __launch_bounds__(256) void k_attn(
    const bf16* __restrict__ q, const bf16* __restrict__ k,
    const bf16* __restrict__ vT, const float* __restrict__ keyBias,
    float* __restrict__ probs, bf16* __restrict__ ctx)
{
    // P tiles: 4 waves x 16 rows x 152 (pad) bf16 = 19456 B.
    // After PV, overlaid by O-combine: 3 x 16 x 68 (pad) fp32 = 13056 B.
    __shared__ __align__(16) char smraw[4 * 16 * 152 * sizeof(bf16)];
    bf16  (*Ps)[16][152] = (bf16 (*)[16][152])smraw;
    float (*Oc)[16][68]  = (float (*)[16][68])smraw;
    __shared__ float redm[4][16];
    __shared__ float reds[4][16];

    int t = threadIdx.x, lane = t & 63, w = t >> 6;
    int l16 = lane & 15, quad = lane >> 4;
    int bh = blockIdx.y, qt = blockIdx.x;
    int qrow = qt * 16;
    int key0 = w * 512;

    // Q A-frags (already scaled by 1/8): rows = qrow + l16, k = quad*8 + j (+32)
    const bf16* qp = q + ((size_t)bh * S_ + qrow + l16) * D_ + quad * 8;
    short8 qf0 = *(const short8*)qp;
    short8 qf1 = *(const short8*)(qp + 32);

    const bf16* kb_ = k + (size_t)bh * S_ * D_;
    const float* kbias = keyBias + bh * S_;

    // ---- QK^T once: 32 independent 16-key tiles, all accumulators live in regs ----
    f32x4 s[32];
#pragma unroll
    for (int kt = 0; kt < 32; ++kt) {
        int key = key0 + kt * 16;
        const bf16* kp = kb_ + (size_t)(key + l16) * D_ + quad * 8;
        short8 kv0 = *(const short8*)kp;
        short8 kv1 = *(const short8*)(kp + 32);
        f32x4 acc = f32x4{0.f, 0.f, 0.f, 0.f};
        acc = mfma16(qf0, kv0, acc);
        acc = mfma16(qf1, kv1, acc);
        s[kt] = acc;
    }
    // add per-key bias (col = key + l16, shared by all 4 rows of the f32x4)
#pragma unroll
    for (int kt = 0; kt < 32; ++kt) {
        float b = kbias[key0 + kt * 16 + l16];
#pragma unroll
        for (int r = 0; r < 4; ++r) s[kt][r] += b;
    }

    // ---- row max: pure fmax tree (no exp on any dependency chain) ----
    float rm[4];
#pragma unroll
    for (int r = 0; r < 4; ++r) rm[r] = s[0][r];
#pragma unroll
    for (int kt = 1; kt < 32; ++kt)
#pragma unroll
        for (int r = 0; r < 4; ++r) rm[r] = fmaxf(rm[r], s[kt][r]);
#pragma unroll
    for (int off = 1; off < 16; off <<= 1)
#pragma unroll
        for (int r = 0; r < 4; ++r) rm[r] = fmaxf(rm[r], __shfl_xor(rm[r], off));
    if (l16 == 0) {
#pragma unroll
        for (int r = 0; r < 4; ++r) redm[w][quad*4 + r] = rm[r];
    }
    __syncthreads();
#pragma unroll
    for (int r = 0; r < 4; ++r) {
        float m = fmaxf(fmaxf(redm[0][quad*4+r], redm[1][quad*4+r]),
                        fmaxf(redm[2][quad*4+r], redm[3][quad*4+r]));
        rm[r] = m;
    }

    // ---- exp in place + row sum ----
    float rl[4] = {0.f, 0.f, 0.f, 0.f};
#pragma unroll
    for (int kt = 0; kt < 32; ++kt)
#pragma unroll
        for (int r = 0; r < 4; ++r) {
            float p = __expf(s[kt][r] - rm[r]);
            s[kt][r] = p;
            rl[r] += p;
        }
#pragma unroll
    for (int off = 1; off < 16; off <<= 1)
#pragma unroll
        for (int r = 0; r < 4; ++r) rl[r] += __shfl_xor(rl[r], off);
    if (l16 == 0) {
#pragma unroll
        for (int r = 0; r < 4; ++r) reds[w][quad*4 + r] = rl[r];
    }
    __syncthreads();
    float invl[4];
#pragma unroll
    for (int r = 0; r < 4; ++r) {
        float l = reds[0][quad*4+r] + reds[1][quad*4+r] + reds[2][quad*4+r] + reds[3][quad*4+r];
        invl[r] = 1.f / l;
    }

    // ---- probs write (exact fp32, from regs) + PV per 128-key chunk ----
    f32x4 o[4];
#pragma unroll
    for (int r = 0; r < 4; ++r) o[r] = f32x4{0.f, 0.f, 0.f, 0.f};
    const bf16* vb = vT + (size_t)bh * D_ * S_;
    float* pr = probs + (size_t)bh * S_ * S_;

    for (int c = 0; c < 4; ++c) {
        int keyc = key0 + c * 128;
#pragma unroll
        for (int nt = 0; nt < 8; ++nt) {
            int kt = c * 8 + nt;
            int key = keyc + nt * 16;
#pragma unroll
            for (int r = 0; r < 4; ++r) {
                float p = s[kt][r] * invl[r];
                pr[(size_t)(qrow + quad*4 + r) * S_ + key + l16] = p;
                Ps[w][quad*4 + r][nt*16 + l16] = __float2bfloat16(p);
            }
        }
        // PV over this 128-key chunk (DS ops in-order within a wave; Ps tile is wave-private)
#pragma unroll
        for (int ks = 0; ks < 4; ++ks) {
            short8 pa = *(const short8*)&Ps[w][l16][ks*32 + quad*8];
#pragma unroll
            for (int dt = 0; dt < 4; ++dt) {
                const bf16* vp = vb + (size_t)(dt*16 + l16) * S_ + keyc + ks*32 + quad*8;
                short8 vv = *(const short8*)vp;
                o[dt] = mfma16(pa, vv, o[dt]);
            }
        }
    }

    // ---- combine O partials across the 4 key-split waves (LDS overlay, dead P tile) ----
    __syncthreads();
    if (w > 0) {
#pragma unroll
        for (int dt = 0; dt < 4; ++dt)
#pragma unroll
            for (int r = 0; r < 4; ++r)
                Oc[w-1][quad*4 + r][dt*16 + l16] = o[dt][r];
    }
    __syncthreads();
    if (w == 0) {
        int b = bh >> 4, h = bh & 15;
#pragma unroll
        for (int dt = 0; dt < 4; ++dt) {
#pragma unroll
            for (int r = 0; r < 4; ++r) {
                float v = o[dt][r] + Oc[0][quad*4+r][dt*16+l16]
                        + Oc[1][quad*4+r][dt*16+l16] + Oc[2][quad*4+r][dt*16+l16];
                int ss = qrow + quad*4 + r;
                int dd = dt*16 + l16;
                ctx[((size_t)b * S_ + ss) * HID_ + h * D_ + dd] = __float2bfloat16(v);
            }
        }
    }
}

// ---------------- launcher ----------------

extern "C" void kernel_launch(void* const* d_in, const int* in_sizes, int n_in,
                              void* d_out, int out_size, void* d_ws, size_t ws_size,
                              hipStream_t stream) {
    (void)in_sizes; (void)n_in; (void)out_size; (void)ws_size;
    const float* hidden = (const float*)d_in[0];
    const float* amask  = (const float*)d_in[1];
    const float* hmask  = (const float*)d_in[2];
    const float* mmask  = (const float*)d_in[3];
    const float* emask  = (const float*)d_in[4];
    const float* Wq = (const float*)d_in[5];  const float* bq = (const float*)d_in[6];
    const float* Wk = (const float*)d_in[7];  const float* bk = (const float*)d_in[8];
    const float* Wv = (const float*)d_in[9];  const float* bv = (const float*)d_in[10];
    const float* Wo = (const float*)d_in[11]; const float* bo = (const float*)d_in[12];
    const float* hb = (const float*)d_in[13];
    const float* mb = (const float*)d_in[14];
    const float* eb = (const float*)d_in[15];

    char* ws = (char*)d_ws;
    bf16* X    = (bf16*)(ws + 0);          //  8 MB
    bf16* Wtq  = (bf16*)(ws + 8388608);    //  2 MB
    bf16* Wtk  = (bf16*)(ws + 10485760);
    bf16* Wtv  = (bf16*)(ws + 12582912);
    bf16* Wto  = (bf16*)(ws + 14680064);
    bf16* qw   = (bf16*)(ws + 16777216);   //  8 MB
    bf16* kw   = (bf16*)(ws + 25165824);   //  8 MB
    bf16* vw   = (bf16*)(ws + 33554432);   //  8 MB
    bf16* vTw  = (bf16*)(ws + 41943040);   //  8 MB
    bf16* ctx  = (bf16*)(ws + 50331648);   //  8 MB
    float* kbias = (float*)(ws + 58720256);// 256 KB   (total ~56.5 MB)

    float* out   = (float*)d_out;
    float* probs = out + (size_t)B_ * S_ * HID_;

    k_convert_x<<<4096, 256, 0, stream>>>(hidden, X, B_ * S_ * HID_);
    dim3 tb(32, 8);
    k_trans_w<<<dim3(32, 32, 4), tb, 0, stream>>>(Wq, Wk, Wv, Wo, Wtq, Wtk, Wtv, Wto);
    k_keybias<<<256, 256, 0, stream>>>(amask, hmask, mmask, emask, hb, mb, eb, kbias);
    k_gemm<true><<<dim3(8, 32, 3), 256, 0, stream>>>(X, Wtq, Wtk, Wtv, bq, bk, bv,
                                                     qw, kw, vw, nullptr);
    k_trans_v<<<dim3(64, 2, 32), tb, 0, stream>>>(vw, vTw);
    k_attn<<<dim3(128, 32), 256, 0, stream>>>(qw, kw, vTw, kbias, probs, ctx);
    k_gemm<false><<<dim3(8, 32, 1), 256, 0, stream>>>(ctx, Wto, Wto, Wto, bo, bo, bo,
                                                      nullptr, nullptr, nullptr, out);
}

// Round 2
// 918.213 us; speedup vs baseline: 1.1549x; 1.0633x over previous
//
#include <hip/hip_runtime.h>
#include <hip/hip_bf16.h>

typedef __hip_bfloat16 bf16;
typedef short short8 __attribute__((ext_vector_type(8)));
typedef float f32x4 __attribute__((ext_vector_type(4)));

#define B_ 2
#define S_ 2048
#define HID_ 1024
#define H_ 16
#define D_ 64
#define M_ (B_*S_)   // 4096 token rows

__device__ __forceinline__ void gload16(const bf16* g, bf16* l) {
    __builtin_amdgcn_global_load_lds(
        (const __attribute__((address_space(1))) unsigned int*)g,
        (__attribute__((address_space(3))) unsigned int*)l, 16, 0, 0);
}

__device__ __forceinline__ f32x4 mfma16(short8 a, short8 b, f32x4 c) {
    return __builtin_amdgcn_mfma_f32_16x16x32_bf16(a, b, c, 0, 0, 0);
}

// ---------------- small prep kernels ----------------

__global__ void k_convert_x(const float* __restrict__ in, bf16* __restrict__ out, int n) {
    int i = blockIdx.x * blockDim.x + threadIdx.x;
    if (i * 4 < n) {
        float4 v = ((const float4*)in)[i];
        out[i*4+0] = __float2bfloat16(v.x);
        out[i*4+1] = __float2bfloat16(v.y);
        out[i*4+2] = __float2bfloat16(v.z);
        out[i*4+3] = __float2bfloat16(v.w);
    }
}

// W [K=in rows][N=out cols] fp32 -> Wt [N][K] bf16, z picks which weight
__global__ void k_trans_w(const float* W0, const float* W1, const float* W2, const float* W3,
                          bf16* T0, bf16* T1, bf16* T2, bf16* T3) {
    const float* W = blockIdx.z==0 ? W0 : blockIdx.z==1 ? W1 : blockIdx.z==2 ? W2 : W3;
    bf16*       T = blockIdx.z==0 ? T0 : blockIdx.z==1 ? T1 : blockIdx.z==2 ? T2 : T3;
    __shared__ float tile[32][33];
    int tx = threadIdx.x, ty = threadIdx.y;
    int k0 = blockIdx.x * 32, n0 = blockIdx.y * 32;
#pragma unroll
    for (int j = 0; j < 4; j++)
        tile[ty + j*8][tx] = W[(size_t)(k0 + ty + j*8) * HID_ + n0 + tx];
    __syncthreads();
#pragma unroll
    for (int j = 0; j < 4; j++)
        T[(size_t)(n0 + ty + j*8) * HID_ + k0 + tx] = __float2bfloat16(tile[tx][ty + j*8]);
}

// keyBias[b,h,k] = attn_mask[b,k] + hb[h]*hm[b,k] + mb[h]*mm[b,k] + eb[h]*em[b,k]
__global__ void k_keybias(const float* __restrict__ am, const float* __restrict__ hm,
                          const float* __restrict__ mm, const float* __restrict__ em,
                          const float* __restrict__ hb, const float* __restrict__ mb,
                          const float* __restrict__ eb, float* __restrict__ kb) {
    int i = blockIdx.x * blockDim.x + threadIdx.x;   // < B*H*S = 65536
    int kk = i & (S_ - 1);
    int bh = i >> 11;
    int h = bh & (H_ - 1);
    int b = bh >> 4;
    int bk = b * S_ + kk;
    kb[i] = am[bk] + hb[h]*hm[bk] + mb[h]*mm[bk] + eb[h]*em[bk];
}

// v [bh][s][d] -> vT [bh][d][s], bf16
__global__ void k_trans_v(const bf16* __restrict__ v, bf16* __restrict__ vT) {
    __shared__ bf16 tile[32][33];
    int bh = blockIdx.z;
    int s0 = blockIdx.x * 32, d0 = blockIdx.y * 32;
    int tx = threadIdx.x, ty = threadIdx.y;
    const bf16* vb = v + (size_t)bh * S_ * D_;
    bf16* vTb = vT + (size_t)bh * D_ * S_;
#pragma unroll
    for (int j = 0; j < 4; j++)
        tile[ty + j*8][tx] = vb[(size_t)(s0 + ty + j*8) * D_ + d0 + tx];
    __syncthreads();
#pragma unroll
    for (int j = 0; j < 4; j++)
        vTb[(size_t)(d0 + ty + j*8) * S_ + s0 + tx] = tile[tx][ty + j*8];
}

// ---------------- 128x128 MFMA GEMM: C = A[M,K] @ Bt[N,K]^T + bias ----------------
// SPLIT=true : out bf16 to [bh][s][d] layout (z=0:q scaled 1/8, 1:k, 2:v)
// SPLIT=false: out fp32 row-major [M, HID]
template<bool SPLIT>
__global__ __launch_bounds__(256) void k_gemm(
    const bf16* __restrict__ A,
    const bf16* __restrict__ Bt0, const bf16* __restrict__ Bt1, const bf16* __restrict__ Bt2,
    const float* __restrict__ bi0, const float* __restrict__ bi1, const float* __restrict__ bi2,
    bf16* d0, bf16* d1, bf16* d2, float* dF)
{
    const int K = HID_;
    int z = blockIdx.z;
    const bf16* Bt = (z==0) ? Bt0 : (z==1 ? Bt1 : Bt2);
    const float* bias = (z==0) ? bi0 : (z==1 ? bi1 : bi2);
    bf16* dst = (z==0) ? d0 : (z==1 ? d1 : d2);
    float scale = (SPLIT && z==0) ? 0.125f : 1.0f;

    __shared__ bf16 As[128*32];
    __shared__ bf16 Bs[128*32];
    int t = threadIdx.x;
    int lane = t & 63, wave = t >> 6;
    int wm = wave >> 1, wn = wave & 1;
    int bm = blockIdx.y * 128, bn = blockIdx.x * 128;

    f32x4 acc[4][4];
#pragma unroll
    for (int i = 0; i < 4; i++)
#pragma unroll
        for (int j = 0; j < 4; j++) acc[i][j] = f32x4{0.f, 0.f, 0.f, 0.f};

    const bf16* aG = A  + (size_t)(bm + (t >> 2)) * K + (t & 3) * 8;
    const bf16* bG = Bt + (size_t)(bn + (t >> 2)) * K + (t & 3) * 8;
    bf16* asD = As + t * 8;
    bf16* bsD = Bs + t * 8;
    int r16 = lane & 15, kq = (lane >> 4) * 8;

    for (int k0 = 0; k0 < K; k0 += 32) {
        __syncthreads();
        gload16(aG + k0,          asD);
        gload16(aG + 64*K + k0,   asD + 2048);
        gload16(bG + k0,          bsD);
        gload16(bG + 64*K + k0,   bsD + 2048);
        __syncthreads();
        short8 af[4], bfv[4];
#pragma unroll
        for (int mt = 0; mt < 4; mt++)
            af[mt] = *(const short8*)(As + (wm*64 + mt*16 + r16) * 32 + kq);
#pragma unroll
        for (int nt = 0; nt < 4; nt++)
            bfv[nt] = *(const short8*)(Bs + (wn*64 + nt*16 + r16) * 32 + kq);
#pragma unroll
        for (int mt = 0; mt < 4; mt++)
#pragma unroll
            for (int nt = 0; nt < 4; nt++)
                acc[mt][nt] = mfma16(af[mt], bfv[nt], acc[mt][nt]);
    }

    int quad = lane >> 4;
#pragma unroll
    for (int mt = 0; mt < 4; mt++) {
#pragma unroll
        for (int nt = 0; nt < 4; nt++) {
            int c = bn + wn*64 + nt*16 + r16;
            int rbase = bm + wm*64 + mt*16 + quad*4;
            float bv = bias[c];
#pragma unroll
            for (int r = 0; r < 4; r++) {
                int m = rbase + r;
                float v = acc[mt][nt][r] + bv;
                if constexpr (SPLIT) {
                    v *= scale;
                    int bb = m >> 11, ss = m & 2047, hh = c >> 6, dd = c & 63;
                    dst[(((size_t)bb * H_ + hh) * S_ + ss) * D_ + dd] = __float2bfloat16(v);
                } else {
                    dF[(size_t)m * HID_ + c] = v;
                }
            }
        }
    }
}

// ---------------- fused attention: single-pass, scores resident in registers ----------------
// grid: (qt=128, bh=32), block 512 (8 waves). Each block: 16 q-rows; wave w owns keys
// [w*256, (w+1)*256). Scores = 16 x f32x4 = 64 VGPR -> total pressure <=128 VGPR so
// __launch_bounds__(512,4) holds 4 waves/SIMD (2x the round-1 occupancy). QK^T computed
// ONCE; exact fp32 probs written from registers; bf16 P round-trips wave-private LDS for
// PV; O-partials combined across the 8 key-split waves via LDS (overlaid on dead P tile).
__global__ __launch_bounds__(512, 4) void k_attn(
    const bf16* __restrict__ q, const bf16* __restrict__ k,
    const bf16* __restrict__ vT, const float* __restrict__ keyBias,
    float* __restrict__ probs, bf16* __restrict__ ctx)
{
    // P tiles: 8 waves x 16 rows x 152 (pad) bf16 = 38912 B.
    // After PV, overlaid by O-combine: 7 x 16 x 68 (pad) fp32 = 30464 B < 38912.
    __shared__ __align__(16) char smraw[8 * 16 * 152 * sizeof(bf16)];
    bf16  (*Ps)[16][152] = (bf16 (*)[16][152])smraw;
    float (*Oc)[16][68]  = (float (*)[16][68])smraw;
    __shared__ float redm[8][16];
    __shared__ float reds[8][16];

    int t = threadIdx.x, lane = t & 63, w = t >> 6;   // w 0..7
    int l16 = lane & 15, quad = lane >> 4;
    int bh = blockIdx.y, qt = blockIdx.x;
    int qrow = qt * 16;
    int key0 = w * 256;

    // Q A-frags (already scaled by 1/8): rows = qrow + l16, k = quad*8 + j (+32)
    const bf16* qp = q + ((size_t)bh * S_ + qrow + l16) * D_ + quad * 8;
    short8 qf0 = *(const short8*)qp;
    short8 qf1 = *(const short8*)(qp + 32);

    const bf16* kb_ = k + (size_t)bh * S_ * D_;
    const float* kbias = keyBias + bh * S_;

    // ---- QK^T once: 16 independent 16-key tiles, accumulators live in regs ----
    f32x4 s[16];
#pragma unroll
    for (int kt = 0; kt < 16; ++kt) {
        int key = key0 + kt * 16;
        const bf16* kp = kb_ + (size_t)(key + l16) * D_ + quad * 8;
        short8 kv0 = *(const short8*)kp;
        short8 kv1 = *(const short8*)(kp + 32);
        f32x4 acc = f32x4{0.f, 0.f, 0.f, 0.f};
        acc = mfma16(qf0, kv0, acc);
        acc = mfma16(qf1, kv1, acc);
        s[kt] = acc;
    }
    // add per-key bias (col = key + l16, shared by all 4 rows of the f32x4)
#pragma unroll
    for (int kt = 0; kt < 16; ++kt) {
        float b = kbias[key0 + kt * 16 + l16];
#pragma unroll
        for (int r = 0; r < 4; ++r) s[kt][r] += b;
    }

    // ---- row max: pure fmax tree (no exp on any dependency chain) ----
    float rm[4];
#pragma unroll
    for (int r = 0; r < 4; ++r) rm[r] = s[0][r];
#pragma unroll
    for (int kt = 1; kt < 16; ++kt)
#pragma unroll
        for (int r = 0; r < 4; ++r) rm[r] = fmaxf(rm[r], s[kt][r]);
#pragma unroll
    for (int off = 1; off < 16; off <<= 1)
#pragma unroll
        for (int r = 0; r < 4; ++r) rm[r] = fmaxf(rm[r], __shfl_xor(rm[r], off));
    if (l16 == 0) {
#pragma unroll
        for (int r = 0; r < 4; ++r) redm[w][quad*4 + r] = rm[r];
    }
    __syncthreads();
#pragma unroll
    for (int r = 0; r < 4; ++r) {
        float m0 = fmaxf(fmaxf(redm[0][quad*4+r], redm[1][quad*4+r]),
                         fmaxf(redm[2][quad*4+r], redm[3][quad*4+r]));
        float m1 = fmaxf(fmaxf(redm[4][quad*4+r], redm[5][quad*4+r]),
                         fmaxf(redm[6][quad*4+r], redm[7][quad*4+r]));
        rm[r] = fmaxf(m0, m1);
    }

    // ---- exp in place + row sum ----
    float rl[4] = {0.f, 0.f, 0.f, 0.f};
#pragma unroll
    for (int kt = 0; kt < 16; ++kt)
#pragma unroll
        for (int r = 0; r < 4; ++r) {
            float p = __expf(s[kt][r] - rm[r]);
            s[kt][r] = p;
            rl[r] += p;
        }
#pragma unroll
    for (int off = 1; off < 16; off <<= 1)
#pragma unroll
        for (int r = 0; r < 4; ++r) rl[r] += __shfl_xor(rl[r], off);
    if (l16 == 0) {
#pragma unroll
        for (int r = 0; r < 4; ++r) reds[w][quad*4 + r] = rl[r];
    }
    __syncthreads();
    float invl[4];
#pragma unroll
    for (int r = 0; r < 4; ++r) {
        float l = reds[0][quad*4+r] + reds[1][quad*4+r] + reds[2][quad*4+r] + reds[3][quad*4+r]
                + reds[4][quad*4+r] + reds[5][quad*4+r] + reds[6][quad*4+r] + reds[7][quad*4+r];
        invl[r] = 1.f / l;
    }

    // ---- probs write (exact fp32, from regs) + PV per 128-key chunk ----
    f32x4 o[4];
#pragma unroll
    for (int r = 0; r < 4; ++r) o[r] = f32x4{0.f, 0.f, 0.f, 0.f};
    const bf16* vb = vT + (size_t)bh * D_ * S_;
    float* pr = probs + (size_t)bh * S_ * S_;

#pragma unroll
    for (int c = 0; c < 2; ++c) {
        int keyc = key0 + c * 128;
#pragma unroll
        for (int nt = 0; nt < 8; ++nt) {
            int kt = c * 8 + nt;
            int key = keyc + nt * 16;
#pragma unroll
            for (int r = 0; r < 4; ++r) {
                float p = s[kt][r] * invl[r];
                pr[(size_t)(qrow + quad*4 + r) * S_ + key + l16] = p;
                Ps[w][quad*4 + r][nt*16 + l16] = __float2bfloat16(p);
            }
        }
        // PV over this 128-key chunk (DS ops in-order within a wave; Ps tile is wave-private)
#pragma unroll
        for (int ks = 0; ks < 4; ++ks) {
            short8 pa = *(const short8*)&Ps[w][l16][ks*32 + quad*8];
#pragma unroll
            for (int dt = 0; dt < 4; ++dt) {
                const bf16* vp = vb + (size_t)(dt*16 + l16) * S_ + keyc + ks*32 + quad*8;
                short8 vv = *(const short8*)vp;
                o[dt] = mfma16(pa, vv, o[dt]);
            }
        }
    }

    // ---- combine O partials across the 8 key-split waves (LDS overlay, dead P tile) ----
    __syncthreads();
    if (w > 0) {
#pragma unroll
        for (int dt = 0; dt < 4; ++dt)
#pragma unroll
            for (int r = 0; r < 4; ++r)
                Oc[w-1][quad*4 + r][dt*16 + l16] = o[dt][r];
    }
    __syncthreads();
    if (w == 0) {
        int b = bh >> 4, h = bh & 15;
#pragma unroll
        for (int dt = 0; dt < 4; ++dt) {
#pragma unroll
            for (int r = 0; r < 4; ++r) {
                float v = o[dt][r];
#pragma unroll
                for (int ww = 0; ww < 7; ++ww)
                    v += Oc[ww][quad*4 + r][dt*16 + l16];
                int ss = qrow + quad*4 + r;
                int dd = dt*16 + l16;
                ctx[((size_t)b * S_ + ss) * HID_ + h * D_ + dd] = __float2bfloat16(v);
            }
        }
    }
}

// ---------------- launcher ----------------

extern "C" void kernel_launch(void* const* d_in, const int* in_sizes, int n_in,
                              void* d_out, int out_size, void* d_ws, size_t ws_size,
                              hipStream_t stream) {
    (void)in_sizes; (void)n_in; (void)out_size; (void)ws_size;
    const float* hidden = (const float*)d_in[0];
    const float* amask  = (const float*)d_in[1];
    const float* hmask  = (const float*)d_in[2];
    const float* mmask  = (const float*)d_in[3];
    const float* emask  = (const float*)d_in[4];
    const float* Wq = (const float*)d_in[5];  const float* bq = (const float*)d_in[6];
    const float* Wk = (const float*)d_in[7];  const float* bk = (const float*)d_in[8];
    const float* Wv = (const float*)d_in[9];  const float* bv = (const float*)d_in[10];
    const float* Wo = (const float*)d_in[11]; const float* bo = (const float*)d_in[12];
    const float* hb = (const float*)d_in[13];
    const float* mb = (const float*)d_in[14];
    const float* eb = (const float*)d_in[15];

    char* ws = (char*)d_ws;
    bf16* X    = (bf16*)(ws + 0);          //  8 MB
    bf16* Wtq  = (bf16*)(ws + 8388608);    //  2 MB
    bf16* Wtk  = (bf16*)(ws + 10485760);
    bf16* Wtv  = (bf16*)(ws + 12582912);
    bf16* Wto  = (bf16*)(ws + 14680064);
    bf16* qw   = (bf16*)(ws + 16777216);   //  8 MB
    bf16* kw   = (bf16*)(ws + 25165824);   //  8 MB
    bf16* vw   = (bf16*)(ws + 33554432);   //  8 MB
    bf16* vTw  = (bf16*)(ws + 41943040);   //  8 MB
    bf16* ctx  = (bf16*)(ws + 50331648);   //  8 MB
    float* kbias = (float*)(ws + 58720256);// 256 KB   (total ~56.5 MB)

    float* out   = (float*)d_out;
    float* probs = out + (size_t)B_ * S_ * HID_;

    k_convert_x<<<4096, 256, 0, stream>>>(hidden, X, B_ * S_ * HID_);
    dim3 tb(32, 8);
    k_trans_w<<<dim3(32, 32, 4), tb, 0, stream>>>(Wq, Wk, Wv, Wo, Wtq, Wtk, Wtv, Wto);
    k_keybias<<<256, 256, 0, stream>>>(amask, hmask, mmask, emask, hb, mb, eb, kbias);
    k_gemm<true><<<dim3(8, 32, 3), 256, 0, stream>>>(X, Wtq, Wtk, Wtv, bq, bk, bv,
                                                     qw, kw, vw, nullptr);
    k_trans_v<<<dim3(64, 2, 32), tb, 0, stream>>>(vw, vTw);
    k_attn<<<dim3(128, 32), 512, 0, stream>>>(qw, kw, vTw, kbias, probs, ctx);
    k_gemm<false><<<dim3(8, 32, 1), 256, 0, stream>>>(ctx, Wto, Wto, Wto, bo, bo, bo,
                                                      nullptr, nullptr, nullptr, out);
}

// Round 3
// 875.370 us; speedup vs baseline: 1.2114x; 1.0489x over previous
//
#include <hip/hip_runtime.h>
#include <hip/hip_bf16.h>

typedef __hip_bfloat16 bf16;
typedef short short8 __attribute__((ext_vector_type(8)));
typedef float f32x4 __attribute__((ext_vector_type(4)));

#define B_ 2
#define S_ 2048
#define HID_ 1024
#define H_ 16
#define D_ 64
#define M_ (B_*S_)   // 4096 token rows

__device__ __forceinline__ void gload16(const bf16* g, bf16* l) {
    __builtin_amdgcn_global_load_lds(
        (const __attribute__((address_space(1))) unsigned int*)g,
        (__attribute__((address_space(3))) unsigned int*)l, 16, 0, 0);
}

__device__ __forceinline__ f32x4 mfma16(short8 a, short8 b, f32x4 c) {
    return __builtin_amdgcn_mfma_f32_16x16x32_bf16(a, b, c, 0, 0, 0);
}

// ---------------- small prep kernels ----------------

__global__ void k_convert_x(const float* __restrict__ in, bf16* __restrict__ out, int n) {
    int i = blockIdx.x * blockDim.x + threadIdx.x;
    if (i * 4 < n) {
        float4 v = ((const float4*)in)[i];
        out[i*4+0] = __float2bfloat16(v.x);
        out[i*4+1] = __float2bfloat16(v.y);
        out[i*4+2] = __float2bfloat16(v.z);
        out[i*4+3] = __float2bfloat16(v.w);
    }
}

// W [K=in rows][N=out cols] fp32 -> Wt [N][K] bf16, z picks which weight
__global__ void k_trans_w(const float* W0, const float* W1, const float* W2, const float* W3,
                          bf16* T0, bf16* T1, bf16* T2, bf16* T3) {
    const float* W = blockIdx.z==0 ? W0 : blockIdx.z==1 ? W1 : blockIdx.z==2 ? W2 : W3;
    bf16*       T = blockIdx.z==0 ? T0 : blockIdx.z==1 ? T1 : blockIdx.z==2 ? T2 : T3;
    __shared__ float tile[32][33];
    int tx = threadIdx.x, ty = threadIdx.y;
    int k0 = blockIdx.x * 32, n0 = blockIdx.y * 32;
#pragma unroll
    for (int j = 0; j < 4; j++)
        tile[ty + j*8][tx] = W[(size_t)(k0 + ty + j*8) * HID_ + n0 + tx];
    __syncthreads();
#pragma unroll
    for (int j = 0; j < 4; j++)
        T[(size_t)(n0 + ty + j*8) * HID_ + k0 + tx] = __float2bfloat16(tile[tx][ty + j*8]);
}

// keyBias[b,h,k] = attn_mask[b,k] + hb[h]*hm[b,k] + mb[h]*mm[b,k] + eb[h]*em[b,k]
__global__ void k_keybias(const float* __restrict__ am, const float* __restrict__ hm,
                          const float* __restrict__ mm, const float* __restrict__ em,
                          const float* __restrict__ hb, const float* __restrict__ mb,
                          const float* __restrict__ eb, float* __restrict__ kb) {
    int i = blockIdx.x * blockDim.x + threadIdx.x;   // < B*H*S = 65536
    int kk = i & (S_ - 1);
    int bh = i >> 11;
    int h = bh & (H_ - 1);
    int b = bh >> 4;
    int bk = b * S_ + kk;
    kb[i] = am[bk] + hb[h]*hm[bk] + mb[h]*mm[bk] + eb[h]*em[bk];
}

// v [bh][s][d] -> vT [bh][d][s], bf16
__global__ void k_trans_v(const bf16* __restrict__ v, bf16* __restrict__ vT) {
    __shared__ bf16 tile[32][33];
    int bh = blockIdx.z;
    int s0 = blockIdx.x * 32, d0 = blockIdx.y * 32;
    int tx = threadIdx.x, ty = threadIdx.y;
    const bf16* vb = v + (size_t)bh * S_ * D_;
    bf16* vTb = vT + (size_t)bh * D_ * S_;
#pragma unroll
    for (int j = 0; j < 4; j++)
        tile[ty + j*8][tx] = vb[(size_t)(s0 + ty + j*8) * D_ + d0 + tx];
    __syncthreads();
#pragma unroll
    for (int j = 0; j < 4; j++)
        vTb[(size_t)(d0 + ty + j*8) * S_ + s0 + tx] = tile[tx][ty + j*8];
}

// ---------------- 128x128 MFMA GEMM: C = A[M,K] @ Bt[N,K]^T + bias ----------------
// SPLIT=true : out bf16 to [bh][s][d] layout (z=0:q scaled 1/8, 1:k, 2:v)
// SPLIT=false: out fp32 row-major [M, HID]
template<bool SPLIT>
__global__ __launch_bounds__(256) void k_gemm(
    const bf16* __restrict__ A,
    const bf16* __restrict__ Bt0, const bf16* __restrict__ Bt1, const bf16* __restrict__ Bt2,
    const float* __restrict__ bi0, const float* __restrict__ bi1, const float* __restrict__ bi2,
    bf16* d0, bf16* d1, bf16* d2, float* dF)
{
    const int K = HID_;
    int z = blockIdx.z;
    const bf16* Bt = (z==0) ? Bt0 : (z==1 ? Bt1 : Bt2);
    const float* bias = (z==0) ? bi0 : (z==1 ? bi1 : bi2);
    bf16* dst = (z==0) ? d0 : (z==1 ? d1 : d2);
    float scale = (SPLIT && z==0) ? 0.125f : 1.0f;

    __shared__ bf16 As[128*32];
    __shared__ bf16 Bs[128*32];
    int t = threadIdx.x;
    int lane = t & 63, wave = t >> 6;
    int wm = wave >> 1, wn = wave & 1;
    int bm = blockIdx.y * 128, bn = blockIdx.x * 128;

    f32x4 acc[4][4];
#pragma unroll
    for (int i = 0; i < 4; i++)
#pragma unroll
        for (int j = 0; j < 4; j++) acc[i][j] = f32x4{0.f, 0.f, 0.f, 0.f};

    const bf16* aG = A  + (size_t)(bm + (t >> 2)) * K + (t & 3) * 8;
    const bf16* bG = Bt + (size_t)(bn + (t >> 2)) * K + (t & 3) * 8;
    bf16* asD = As + t * 8;
    bf16* bsD = Bs + t * 8;
    int r16 = lane & 15, kq = (lane >> 4) * 8;

    for (int k0 = 0; k0 < K; k0 += 32) {
        __syncthreads();
        gload16(aG + k0,          asD);
        gload16(aG + 64*K + k0,   asD + 2048);
        gload16(bG + k0,          bsD);
        gload16(bG + 64*K + k0,   bsD + 2048);
        __syncthreads();
        short8 af[4], bfv[4];
#pragma unroll
        for (int mt = 0; mt < 4; mt++)
            af[mt] = *(const short8*)(As + (wm*64 + mt*16 + r16) * 32 + kq);
#pragma unroll
        for (int nt = 0; nt < 4; nt++)
            bfv[nt] = *(const short8*)(Bs + (wn*64 + nt*16 + r16) * 32 + kq);
#pragma unroll
        for (int mt = 0; mt < 4; mt++)
#pragma unroll
            for (int nt = 0; nt < 4; nt++)
                acc[mt][nt] = mfma16(af[mt], bfv[nt], acc[mt][nt]);
    }

    int quad = lane >> 4;
#pragma unroll
    for (int mt = 0; mt < 4; mt++) {
#pragma unroll
        for (int nt = 0; nt < 4; nt++) {
            int c = bn + wn*64 + nt*16 + r16;
            int rbase = bm + wm*64 + mt*16 + quad*4;
            float bv = bias[c];
#pragma unroll
            for (int r = 0; r < 4; r++) {
                int m = rbase + r;
                float v = acc[mt][nt][r] + bv;
                if constexpr (SPLIT) {
                    v *= scale;
                    int bb = m >> 11, ss = m & 2047, hh = c >> 6, dd = c & 63;
                    dst[(((size_t)bb * H_ + hh) * S_ + ss) * D_ + dd] = __float2bfloat16(v);
                } else {
                    dF[(size_t)m * HID_ + c] = v;
                }
            }
        }
    }
}

// ---------------- fused attention: single-pass, scores resident in registers ----------------
// grid: (qt=128, bh=32), block 512 (8 waves). Each block: 16 q-rows; wave w owns keys
// [w*256, (w+1)*256). Scores = 16 x f32x4 = 64 VGPR; __launch_bounds__(512,4) caps at 128.
// QK^T computed ONCE (K-loads batched 4-deep for latency overlap); probs written as
// LDS-transposed fp32 dwordx4 NONTEMPORAL stores (write-once stream, bypass L2);
// bf16 P round-trips wave-private LDS for PV; O-partials combined across waves via LDS.
__global__ __launch_bounds__(512, 4) void k_attn(
    const bf16* __restrict__ q, const bf16* __restrict__ k,
    const bf16* __restrict__ vT, const float* __restrict__ keyBias,
    float* __restrict__ probs, bf16* __restrict__ ctx)
{
    // P tiles: 8 waves x 16 rows x 152 (pad) bf16 = 38912 B.
    // After PV, overlaid by O-combine: 7 x 16 x 68 (pad) fp32 = 30464 B < 38912.
    __shared__ __align__(16) char smraw[8 * 16 * 152 * sizeof(bf16)];
    bf16  (*Ps)[16][152] = (bf16 (*)[16][152])smraw;
    float (*Oc)[16][68]  = (float (*)[16][68])smraw;
    // fp32 transpose staging for vectorized probs stores: [16 rows][20 pad] per wave.
    // pad=20 -> store side 2-way bank alias max (free), read side b128 16B-aligned.
    __shared__ __align__(16) float Pt[8][16][20];
    __shared__ float redm[8][16];
    __shared__ float reds[8][16];

    int t = threadIdx.x, lane = t & 63, w = t >> 6;   // w 0..7
    int l16 = lane & 15, quad = lane >> 4;
    int bh = blockIdx.y, qt = blockIdx.x;
    int qrow = qt * 16;
    int key0 = w * 256;

    // Q A-frags (already scaled by 1/8): rows = qrow + l16, k = quad*8 + j (+32)
    const bf16* qp = q + ((size_t)bh * S_ + qrow + l16) * D_ + quad * 8;
    short8 qf0 = *(const short8*)qp;
    short8 qf1 = *(const short8*)(qp + 32);

    const bf16* kb_ = k + (size_t)bh * S_ * D_;
    const float* kbias = keyBias + bh * S_;

    // ---- QK^T once: 16 independent 16-key tiles; K-loads batched 4-deep ----
    f32x4 s[16];
#pragma unroll
    for (int g = 0; g < 4; ++g) {
        short8 ka[4], kb2[4];
#pragma unroll
        for (int j = 0; j < 4; ++j) {
            int key = key0 + (g*4 + j) * 16;
            const bf16* kp = kb_ + (size_t)(key + l16) * D_ + quad * 8;
            ka[j]  = *(const short8*)kp;
            kb2[j] = *(const short8*)(kp + 32);
        }
#pragma unroll
        for (int j = 0; j < 4; ++j) {
            f32x4 acc = f32x4{0.f, 0.f, 0.f, 0.f};
            acc = mfma16(qf0, ka[j], acc);
            acc = mfma16(qf1, kb2[j], acc);
            s[g*4 + j] = acc;
        }
    }
    // add per-key bias (col = key + l16, shared by all 4 rows of the f32x4)
#pragma unroll
    for (int kt = 0; kt < 16; ++kt) {
        float b = kbias[key0 + kt * 16 + l16];
#pragma unroll
        for (int r = 0; r < 4; ++r) s[kt][r] += b;
    }

    // ---- row max: pure fmax tree (no exp on any dependency chain) ----
    float rm[4];
#pragma unroll
    for (int r = 0; r < 4; ++r) rm[r] = s[0][r];
#pragma unroll
    for (int kt = 1; kt < 16; ++kt)
#pragma unroll
        for (int r = 0; r < 4; ++r) rm[r] = fmaxf(rm[r], s[kt][r]);
#pragma unroll
    for (int off = 1; off < 16; off <<= 1)
#pragma unroll
        for (int r = 0; r < 4; ++r) rm[r] = fmaxf(rm[r], __shfl_xor(rm[r], off));
    if (l16 == 0) {
#pragma unroll
        for (int r = 0; r < 4; ++r) redm[w][quad*4 + r] = rm[r];
    }
    __syncthreads();
#pragma unroll
    for (int r = 0; r < 4; ++r) {
        float m0 = fmaxf(fmaxf(redm[0][quad*4+r], redm[1][quad*4+r]),
                         fmaxf(redm[2][quad*4+r], redm[3][quad*4+r]));
        float m1 = fmaxf(fmaxf(redm[4][quad*4+r], redm[5][quad*4+r]),
                         fmaxf(redm[6][quad*4+r], redm[7][quad*4+r]));
        rm[r] = fmaxf(m0, m1);
    }

    // ---- exp in place + row sum ----
    float rl[4] = {0.f, 0.f, 0.f, 0.f};
#pragma unroll
    for (int kt = 0; kt < 16; ++kt)
#pragma unroll
        for (int r = 0; r < 4; ++r) {
            float p = __expf(s[kt][r] - rm[r]);
            s[kt][r] = p;
            rl[r] += p;
        }
#pragma unroll
    for (int off = 1; off < 16; off <<= 1)
#pragma unroll
        for (int r = 0; r < 4; ++r) rl[r] += __shfl_xor(rl[r], off);
    if (l16 == 0) {
#pragma unroll
        for (int r = 0; r < 4; ++r) reds[w][quad*4 + r] = rl[r];
    }
    __syncthreads();
    float invl[4];
#pragma unroll
    for (int r = 0; r < 4; ++r) {
        float l = reds[0][quad*4+r] + reds[1][quad*4+r] + reds[2][quad*4+r] + reds[3][quad*4+r]
                + reds[4][quad*4+r] + reds[5][quad*4+r] + reds[6][quad*4+r] + reds[7][quad*4+r];
        invl[r] = 1.f / l;
    }

    // ---- probs write (LDS-transposed fp32 -> dwordx4 NT stores) + PV per 128-key chunk ----
    f32x4 o[4];
#pragma unroll
    for (int r = 0; r < 4; ++r) o[r] = f32x4{0.f, 0.f, 0.f, 0.f};
    const bf16* vb = vT + (size_t)bh * D_ * S_;
    float* pr = probs + (size_t)bh * S_ * S_;
    int prow = lane & 15, pseg = lane >> 4;   // transpose-read mapping

#pragma unroll
    for (int c = 0; c < 2; ++c) {
        int keyc = key0 + c * 128;
#pragma unroll
        for (int nt = 0; nt < 8; ++nt) {
            int kt = c * 8 + nt;
            int key = keyc + nt * 16;
#pragma unroll
            for (int r = 0; r < 4; ++r) {
                float p = s[kt][r] * invl[r];
                Pt[w][quad*4 + r][l16] = p;                       // fp32 for transpose-store
                Ps[w][quad*4 + r][nt*16 + l16] = __float2bfloat16(p);  // bf16 for PV
            }
            // wave-private LDS, DS ops in-order per wave: safe to read the full tile now.
            f32x4 tp = *(const f32x4*)&Pt[w][prow][pseg * 4];
            __builtin_nontemporal_store(
                tp, (f32x4*)&pr[(size_t)(qrow + prow) * S_ + key + pseg * 4]);
        }
        // PV over this 128-key chunk (DS ops in-order within a wave; Ps tile is wave-private)
#pragma unroll
        for (int ks = 0; ks < 4; ++ks) {
            short8 pa = *(const short8*)&Ps[w][l16][ks*32 + quad*8];
#pragma unroll
            for (int dt = 0; dt < 4; ++dt) {
                const bf16* vp = vb + (size_t)(dt*16 + l16) * S_ + keyc + ks*32 + quad*8;
                short8 vv = *(const short8*)vp;
                o[dt] = mfma16(pa, vv, o[dt]);
            }
        }
    }

    // ---- combine O partials across the 8 key-split waves (LDS overlay, dead P tile) ----
    __syncthreads();
    if (w > 0) {
#pragma unroll
        for (int dt = 0; dt < 4; ++dt)
#pragma unroll
            for (int r = 0; r < 4; ++r)
                Oc[w-1][quad*4 + r][dt*16 + l16] = o[dt][r];
    }
    __syncthreads();
    if (w == 0) {
        int b = bh >> 4, h = bh & 15;
#pragma unroll
        for (int dt = 0; dt < 4; ++dt) {
#pragma unroll
            for (int r = 0; r < 4; ++r) {
                float v = o[dt][r];
#pragma unroll
                for (int ww = 0; ww < 7; ++ww)
                    v += Oc[ww][quad*4 + r][dt*16 + l16];
                int ss = qrow + quad*4 + r;
                int dd = dt*16 + l16;
                ctx[((size_t)b * S_ + ss) * HID_ + h * D_ + dd] = __float2bfloat16(v);
            }
        }
    }
}

// ---------------- launcher ----------------

extern "C" void kernel_launch(void* const* d_in, const int* in_sizes, int n_in,
                              void* d_out, int out_size, void* d_ws, size_t ws_size,
                              hipStream_t stream) {
    (void)in_sizes; (void)n_in; (void)out_size; (void)ws_size;
    const float* hidden = (const float*)d_in[0];
    const float* amask  = (const float*)d_in[1];
    const float* hmask  = (const float*)d_in[2];
    const float* mmask  = (const float*)d_in[3];
    const float* emask  = (const float*)d_in[4];
    const float* Wq = (const float*)d_in[5];  const float* bq = (const float*)d_in[6];
    const float* Wk = (const float*)d_in[7];  const float* bk = (const float*)d_in[8];
    const float* Wv = (const float*)d_in[9];  const float* bv = (const float*)d_in[10];
    const float* Wo = (const float*)d_in[11]; const float* bo = (const float*)d_in[12];
    const float* hb = (const float*)d_in[13];
    const float* mb = (const float*)d_in[14];
    const float* eb = (const float*)d_in[15];

    char* ws = (char*)d_ws;
    bf16* X    = (bf16*)(ws + 0);          //  8 MB
    bf16* Wtq  = (bf16*)(ws + 8388608);    //  2 MB
    bf16* Wtk  = (bf16*)(ws + 10485760);
    bf16* Wtv  = (bf16*)(ws + 12582912);
    bf16* Wto  = (bf16*)(ws + 14680064);
    bf16* qw   = (bf16*)(ws + 16777216);   //  8 MB
    bf16* kw   = (bf16*)(ws + 25165824);   //  8 MB
    bf16* vw   = (bf16*)(ws + 33554432);   //  8 MB
    bf16* vTw  = (bf16*)(ws + 41943040);   //  8 MB
    bf16* ctx  = (bf16*)(ws + 50331648);   //  8 MB
    float* kbias = (float*)(ws + 58720256);// 256 KB   (total ~56.5 MB)

    float* out   = (float*)d_out;
    float* probs = out + (size_t)B_ * S_ * HID_;

    k_convert_x<<<4096, 256, 0, stream>>>(hidden, X, B_ * S_ * HID_);
    dim3 tb(32, 8);
    k_trans_w<<<dim3(32, 32, 4), tb, 0, stream>>>(Wq, Wk, Wv, Wo, Wtq, Wtk, Wtv, Wto);
    k_keybias<<<256, 256, 0, stream>>>(amask, hmask, mmask, emask, hb, mb, eb, kbias);
    k_gemm<true><<<dim3(8, 32, 3), 256, 0, stream>>>(X, Wtq, Wtk, Wtv, bq, bk, bv,
                                                     qw, kw, vw, nullptr);
    k_trans_v<<<dim3(64, 2, 32), tb, 0, stream>>>(vw, vTw);
    k_attn<<<dim3(128, 32), 512, 0, stream>>>(qw, kw, vTw, kbias, probs, ctx);
    k_gemm<false><<<dim3(8, 32, 1), 256, 0, stream>>>(ctx, Wto, Wto, Wto, bo, bo, bo,
                                                      nullptr, nullptr, nullptr, out);
}